// Round 14
// baseline (275.165 us; speedup 1.0000x reference)
//
#include <hip/hip_runtime.h>
#include <hip/hip_bf16.h>

#define HW 4096
#define CC 256
#define NBATCH 8
#define EPSF 1e-6f
#define SCL1 0x7F7F7F7F       // E8M0 exponent 127 -> scale 1.0 in all bytes
#define LOG2E 1.44269504089f
#define C2L   2.88539008177f  // 2*log2(e)

typedef __attribute__((ext_vector_type(4))) float floatx4;
typedef __attribute__((ext_vector_type(8))) int intx8;
typedef long long llong;

union U8 { intx8 v; llong d[4]; };

// raw v_exp_f32: D = 2^S0 (1 VALU op; OCML exp2f is a multi-op fixup path)
#define EXP2(x) __builtin_amdgcn_exp2f(x)

// async global->LDS, 16B per lane (lds dst = uniform base + lane*16)
#define GLDS(g, l) __builtin_amdgcn_global_load_lds( \
    (const __attribute__((address_space(1))) void*)(const void*)(g), \
    (__attribute__((address_space(3))) void*)(void*)(l), 16, 0, 0)

// monotone float <-> unsigned key (order-preserving)
__device__ __forceinline__ unsigned fkey(float f){
    unsigned u = __float_as_uint(f);
    return (u & 0x80000000u) ? ~u : (u | 0x80000000u);
}
__device__ __forceinline__ float fdec(unsigned k){
    unsigned u = (k & 0x80000000u) ? (k ^ 0x80000000u) : ~k;
    return __uint_as_float(u);
}
__device__ __forceinline__ unsigned short f2bf(float f){
    unsigned u = __float_as_uint(f);
    u += 0x7FFFu + ((u >> 16) & 1);
    return (unsigned short)(u >> 16);
}

// ---------------- kernel 1: per-channel mean of y ----------------
__global__ __launch_bounds__(256) void kmean(const float* __restrict__ y,
                                             float* __restrict__ ymu){
    const int c = blockIdx.x;
    const int t = threadIdx.x;
    float s = 0.f;
    for(int n = 0; n < NBATCH; n++){
        const float4* p = reinterpret_cast<const float4*>(y + ((size_t)n*CC + c)*HW);
        #pragma unroll
        for(int i = 0; i < 4; i++){
            float4 v = p[i*256 + t];
            s += (v.x + v.y) + (v.z + v.w);
        }
    }
    __shared__ float red[256];
    red[t] = s; __syncthreads();
    for(int off = 128; off > 0; off >>= 1){
        if(t < off) red[t] += red[t+off];
        __syncthreads();
    }
    if(t == 0) ymu[c] = red[0] * (1.0f/((float)NBATCH*HW));
}

// ---- kernel 2: center, normalize over C, emit MFMA-fragment-major FP8 ----
// fp8 layout per batch (1 MB): addr(i,c) = (i>>4)*4096 + kt*512 + q*128 + (i&15)*8 + e
//   where c = kt*32 + q*8 + e.  blockIdx.z selects x vs y (de-serialized).
// Also inits dmink/rowsum/colmaxk (z==0 blocks only).
#define TROW 266
__global__ __launch_bounds__(256) void knorm(const float* __restrict__ x,
                                             const float* __restrict__ y,
                                             const float* __restrict__ ymu,
                                             unsigned char* __restrict__ xF,
                                             unsigned char* __restrict__ yF,
                                             unsigned* __restrict__ dmink,
                                             float* __restrict__ rowsum,
                                             unsigned* __restrict__ colmaxk){
    __shared__ __align__(16) unsigned short tile[64*TROW];
    __shared__ float invn[64];
    __shared__ float partial16[16][64];
    __shared__ float smu[CC];
    const int t   = threadIdx.x;
    const int hw0 = blockIdx.x * 64;
    const int n   = blockIdx.y;
    const int which = blockIdx.z;
    if(which == 0 && t < 64){
        size_t g = (size_t)n*HW + hw0 + t;
        dmink[g] = 0xFFFFFFFFu;
        rowsum[g] = 0.f;
        colmaxk[g] = 0u;
    }
    for(int c = t; c < CC; c += 256) smu[c] = ymu[c];
    const int cgrp = t >> 4;   // 0..15
    const int hwg  = t & 15;   // 0..15 (x4 hw each)
    const float* __restrict__ src = which ? y : x;
    unsigned char* __restrict__ dst = which ? yF : xF;
    __syncthreads();
    float ss4[4] = {0.f, 0.f, 0.f, 0.f};
    #pragma unroll
    for(int cc = 0; cc < 16; cc++){
        int c = cc*16 + cgrp;
        float4 v4 = *reinterpret_cast<const float4*>(
            &src[((size_t)n*CC + c)*HW + hw0 + hwg*4]);
        float mu = smu[c];
        float f0 = v4.x - mu, f1 = v4.y - mu, f2 = v4.z - mu, f3 = v4.w - mu;
        ss4[0] += f0*f0; ss4[1] += f1*f1; ss4[2] += f2*f2; ss4[3] += f3*f3;
        tile[(hwg*4+0)*TROW + c] = f2bf(f0);
        tile[(hwg*4+1)*TROW + c] = f2bf(f1);
        tile[(hwg*4+2)*TROW + c] = f2bf(f2);
        tile[(hwg*4+3)*TROW + c] = f2bf(f3);
    }
    #pragma unroll
    for(int e = 0; e < 4; e++) partial16[cgrp][hwg*4+e] = ss4[e];
    __syncthreads();
    if(t < 64){
        float s = 0.f;
        #pragma unroll
        for(int g2 = 0; g2 < 16; g2++) s += partial16[g2][t];
        invn[t] = rsqrtf(s);
    }
    __syncthreads();
    size_t base = ((size_t)n << 20) + (size_t)(hw0 >> 4)*4096;
    #pragma unroll
    for(int v4i = 0; v4i < 4; v4i++){
        int g  = v4i*256 + t;           // 0..1023, unit = 16 fp8 (2 rows x 8 c)
        int it = g >> 8;
        int kt = (g >> 5) & 7;
        int qq = (g >> 3) & 3;
        int u  = g & 7;
        int r0 = it*16 + u*2;
        unsigned w[4];
        #pragma unroll
        for(int rr = 0; rr < 2; rr++){
            int r = r0 + rr;
            float inv = invn[r];
            const unsigned* lp = reinterpret_cast<const unsigned*>(&tile[r*TROW + kt*32 + qq*8]);
            float f[8];
            #pragma unroll
            for(int w2 = 0; w2 < 4; w2++){
                unsigned uu = lp[w2];
                f[2*w2]   = __uint_as_float((uu & 0xFFFFu) << 16) * inv;
                f[2*w2+1] = __uint_as_float(uu & 0xFFFF0000u) * inv;
            }
            unsigned wa = 0, wb = 0;
            wa = __builtin_amdgcn_cvt_pk_fp8_f32(f[0], f[1], wa, false);
            wa = __builtin_amdgcn_cvt_pk_fp8_f32(f[2], f[3], wa, true);
            wb = __builtin_amdgcn_cvt_pk_fp8_f32(f[4], f[5], wb, false);
            wb = __builtin_amdgcn_cvt_pk_fp8_f32(f[6], f[7], wb, true);
            w[2*rr] = wa; w[2*rr+1] = wb;
        }
        uint4 ov; ov.x=w[0]; ov.y=w[1]; ov.z=w[2]; ov.w=w[3];
        *reinterpret_cast<uint4*>(dst + base + it*4096 + kt*512 + qq*128 + u*16) = ov;
    }
}

// ---- sweep kernels: block = 512 i (4 waves x 128 i in regs) x 512-j slice.
// MX-scaled MFMA 16x16x128 fp8 (unit scales) = 2x rate of plain fp8.
// B staged via global_load_lds in 16KB super-tiles (4 js-tiles of 16 j),
// double-buffered, one barrier per 4 js.  Straight-line b-loads only
// (R11's breg[] went to scratch).  Epilogue exp = raw v_exp_f32.
// Per-row constants folded: exponent = acc*scS + bbS (single fma/elem).
// MODE 0: dmin   1: rowsum (bbS = C2L-sc)   2: colmax (bbS = C2L-sc-log2 rs)
template<int MODE>
__global__ __launch_bounds__(256, 2) void ksweep(
        const unsigned char* __restrict__ xF,
        const unsigned char* __restrict__ yF,
        unsigned* __restrict__ dmink,
        float* __restrict__ rowsum,
        unsigned* __restrict__ colmaxk){
    __shared__ __align__(16) unsigned char Bs[2][16384];
    __shared__ __align__(16) float scS[4][128];
    __shared__ __align__(16) float bbS[4][128];
    const int t    = threadIdx.x;
    const int lane = t & 63;
    const int wave = t >> 6;
    const int q    = lane >> 4;
    const int l15  = lane & 15;
    const int bid  = blockIdx.x;
    const int n    = bid & 7;          // batch <-> XCD affinity
    const int rem  = bid >> 3;
    const int ip   = rem & 7;          // i-panel (512 rows)
    const int jq   = rem >> 3;         // j slice (512 cols)
    const size_t nb8 = (size_t)n << 20;
    const size_t nbw = (size_t)n * HW;
    const int iw   = ip*512 + wave*128;   // this wave's 128 rows
    const unsigned char* Ax = xF + nb8 + (size_t)(iw >> 4)*4096 + q*512 + l15*8;
    const unsigned char* Yb = yF + nb8 + (size_t)jq*131072;   // 512 j * 256 B

    // A fragments: af0 = k[q*32..+32), af1 = k[128+q*32..+32)
    U8 af0[8], af1[8];
    #pragma unroll
    for(int ti = 0; ti < 8; ti++)
        #pragma unroll
        for(int qq = 0; qq < 4; qq++){
            af0[ti].d[qq] = *reinterpret_cast<const llong*>(Ax + ti*4096 + qq*128);
            af1[ti].d[qq] = *reinterpret_cast<const llong*>(Ax + ti*4096 + 2048 + qq*128);
        }

    if(MODE >= 1){
        // per-row scS/bbS -> wave-private broadcast LDS (2 rows per lane)
        #pragma unroll
        for(int rr = 0; rr < 2; rr++){
            int row = lane*2 + rr;
            size_t g = nbw + iw + row;
            float sc = (2.f / (fdec(dmink[g]) + EPSF)) * LOG2E;
            scS[wave][row] = sc;
            bbS[wave][row] = (MODE == 1) ? (C2L - sc)
                                         : (C2L - sc - __log2f(rowsum[g]));
        }
    }
    float racc[8][4];
    #pragma unroll
    for(int ti = 0; ti < 8; ti++)
        #pragma unroll
        for(int r = 0; r < 4; r++) racc[ti][r] = (MODE == 0) ? -3e38f : 0.f;

    // prologue: stage super-tile 0 (16KB; 4KB per wave = 4 x 1KB chunks)
    #pragma unroll
    for(int p = 0; p < 4; p++){
        int c = wave*4 + p;
        GLDS(Yb + c*1024 + (size_t)lane*16, &Bs[0][c*1024]);
    }
    __syncthreads();

    #pragma unroll 1
    for(int ss = 0; ss < 8; ss++){
        // stage next super-tile (ss=7 overreads 16KB into slack; harmless)
        {
            const unsigned char* src = Yb + (size_t)(ss+1)*16384;
            unsigned char* dstb = Bs[(ss+1)&1];
            #pragma unroll
            for(int p = 0; p < 4; p++){
                int c = wave*4 + p;
                GLDS(src + c*1024 + (size_t)lane*16, &dstb[c*1024]);
            }
        }
        #pragma unroll 1
        for(int u = 0; u < 4; u++){
            const unsigned char* Bq = &Bs[ss&1][u*4096] + q*512 + l15*8;
            const int js = ss*4 + u;
            U8 b0, b1;
            #pragma unroll
            for(int qq = 0; qq < 4; qq++){
                b0.d[qq] = *reinterpret_cast<const llong*>(Bq + qq*128);
                b1.d[qq] = *reinterpret_cast<const llong*>(Bq + 2048 + qq*128);
            }
            floatx4 acc[8];
            #pragma unroll
            for(int a = 0; a < 8; a++) acc[a] = (floatx4){0.f,0.f,0.f,0.f};
            #pragma unroll
            for(int ti = 0; ti < 8; ti++){
                acc[ti] = __builtin_amdgcn_mfma_scale_f32_16x16x128_f8f6f4(
                              af0[ti].v, b0.v, acc[ti], 0, 0, 0, SCL1, 0, SCL1);
                acc[ti] = __builtin_amdgcn_mfma_scale_f32_16x16x128_f8f6f4(
                              af1[ti].v, b1.v, acc[ti], 0, 0, 0, SCL1, 0, SCL1);
            }
            if(MODE == 0){
                #pragma unroll
                for(int ti = 0; ti < 8; ti++)
                    #pragma unroll
                    for(int r = 0; r < 4; r++)
                        racc[ti][r] = fmaxf(racc[ti][r], acc[ti][r]);
            } else if(MODE == 1){
                #pragma unroll
                for(int ti = 0; ti < 8; ti++){
                    const floatx4 sc4 = *reinterpret_cast<const floatx4*>(&scS[wave][ti*16 + q*4]);
                    const floatx4 bb4 = *reinterpret_cast<const floatx4*>(&bbS[wave][ti*16 + q*4]);
                    #pragma unroll
                    for(int r = 0; r < 4; r++)
                        racc[ti][r] += EXP2(fmaf(acc[ti][r], sc4[r], bb4[r]));
                }
            } else {
                float a = -3e38f;
                #pragma unroll
                for(int ti = 0; ti < 8; ti++){
                    const floatx4 sc4 = *reinterpret_cast<const floatx4*>(&scS[wave][ti*16 + q*4]);
                    const floatx4 bb4 = *reinterpret_cast<const floatx4*>(&bbS[wave][ti*16 + q*4]);
                    #pragma unroll
                    for(int r = 0; r < 4; r++)
                        a = fmaxf(a, fmaf(acc[ti][r], sc4[r], bb4[r]));
                }
                a = fmaxf(a, __shfl_xor(a, 16));
                a = fmaxf(a, __shfl_xor(a, 32));
                if(lane < 16)
                    atomicMax(&colmaxk[nbw + jq*512 + js*16 + l15], fkey(EXP2(a)));
            }
        }
        __syncthreads();
    }

    if(MODE == 0){
        #pragma unroll
        for(int ti = 0; ti < 8; ti++)
            #pragma unroll
            for(int r = 0; r < 4; r++){
                float v = racc[ti][r];
                v = fmaxf(v, __shfl_xor(v, 1));
                v = fmaxf(v, __shfl_xor(v, 2));
                v = fmaxf(v, __shfl_xor(v, 4));
                v = fmaxf(v, __shfl_xor(v, 8));
                if(l15 == 0)
                    atomicMin(&dmink[nbw + iw + ti*16 + q*4 + r], fkey(1.f - v));
            }
    } else if(MODE == 1){
        #pragma unroll
        for(int ti = 0; ti < 8; ti++)
            #pragma unroll
            for(int r = 0; r < 4; r++){
                float v = racc[ti][r];
                v += __shfl_xor(v, 1);
                v += __shfl_xor(v, 2);
                v += __shfl_xor(v, 4);
                v += __shfl_xor(v, 8);
                if(l15 == 0)
                    atomicAdd(&rowsum[nbw + iw + ti*16 + q*4 + r], v);
            }
    }
}

// ---------------- final: per-batch partial, then tiny reduce ----------------
__global__ __launch_bounds__(256) void kpart(const unsigned* __restrict__ colmaxk,
                                             float* __restrict__ part){
    __shared__ float red[256];
    const int t = threadIdx.x;
    const int n = blockIdx.x;
    float s = 0.f;
    for(int j = t; j < HW; j += 256) s += fdec(colmaxk[(size_t)n*HW + j]);
    red[t] = s; __syncthreads();
    for(int off = 128; off > 0; off >>= 1){
        if(t < off) red[t] += red[t+off];
        __syncthreads();
    }
    if(t == 0) part[n] = -logf(red[0]*(1.0f/HW) + EPSF);
}

__global__ __launch_bounds__(64) void kfin(const float* __restrict__ part,
                                           float* __restrict__ out){
    const int t = threadIdx.x;
    float v = (t < NBATCH) ? part[t] : 0.f;
    v += __shfl_xor(v, 1);
    v += __shfl_xor(v, 2);
    v += __shfl_xor(v, 4);
    if(t == 0) out[0] = v * (1.0f/NBATCH);
}

extern "C" void kernel_launch(void* const* d_in, const int* in_sizes, int n_in,
                              void* d_out, int out_size, void* d_ws, size_t ws_size,
                              hipStream_t stream){
    const float* x = (const float*)d_in[0];
    const float* y = (const float*)d_in[1];
    float* out = (float*)d_out;
    char* ws = (char*)d_ws;

    float* ymu = (float*)ws;
    size_t off = 1024;
    unsigned char* xF = (unsigned char*)(ws + off); off += (size_t)NBATCH << 20;
    unsigned char* yF = (unsigned char*)(ws + off); off += ((size_t)NBATCH << 20) + (512<<10); // tail-prefetch slack
    unsigned* dmink   = (unsigned*)(ws + off);      off += (size_t)NBATCH*HW*4;
    float* rowsum     = (float*)(ws + off);         off += (size_t)NBATCH*HW*4;
    unsigned* colmaxk = (unsigned*)(ws + off);      off += (size_t)NBATCH*HW*4;
    float* part       = (float*)(ws + off);         off += 64;

    kmean<<<dim3(CC), dim3(256), 0, stream>>>(y, ymu);
    knorm<<<dim3(HW/64, NBATCH, 2), dim3(256), 0, stream>>>(x, y, ymu, xF, yF,
                                                            dmink, rowsum, colmaxk);
    ksweep<0><<<dim3(512), dim3(256), 0, stream>>>(xF, yF, dmink, rowsum, colmaxk);
    ksweep<1><<<dim3(512), dim3(256), 0, stream>>>(xF, yF, dmink, rowsum, colmaxk);
    ksweep<2><<<dim3(512), dim3(256), 0, stream>>>(xF, yF, dmink, rowsum, colmaxk);
    kpart<<<dim3(NBATCH), dim3(256), 0, stream>>>(colmaxk, part);
    kfin<<<dim3(1), dim3(64), 0, stream>>>(part, out);
}

// Round 15
// 219.601 us; speedup vs baseline: 1.2530x; 1.2530x over previous
//
#include <hip/hip_runtime.h>
#include <hip/hip_bf16.h>

#define HW 4096
#define CC 256
#define NBATCH 8
#define EPSF 1e-6f
#define SCL1 0x7F7F7F7F       // E8M0 exponent 127 -> scale 1.0 in all bytes
#define LOG2E 1.44269504089f
#define C2L   2.88539008177f  // 2*log2(e)

typedef __attribute__((ext_vector_type(4))) float floatx4;
typedef __attribute__((ext_vector_type(8))) int intx8;
typedef long long llong;

union U8 { intx8 v; llong d[4]; };

// raw v_exp_f32: D = 2^S0 (1 VALU op; OCML exp2f is a multi-op fixup path)
#define EXP2(x) __builtin_amdgcn_exp2f(x)

// async global->LDS, 16B per lane (lds dst = uniform base + lane*16)
#define GLDS(g, l) __builtin_amdgcn_global_load_lds( \
    (const __attribute__((address_space(1))) void*)(const void*)(g), \
    (__attribute__((address_space(3))) void*)(void*)(l), 16, 0, 0)

// monotone float <-> unsigned key (order-preserving)
__device__ __forceinline__ unsigned fkey(float f){
    unsigned u = __float_as_uint(f);
    return (u & 0x80000000u) ? ~u : (u | 0x80000000u);
}
__device__ __forceinline__ float fdec(unsigned k){
    unsigned u = (k & 0x80000000u) ? (k ^ 0x80000000u) : ~k;
    return __uint_as_float(u);
}
__device__ __forceinline__ unsigned short f2bf(float f){
    unsigned u = __float_as_uint(f);
    u += 0x7FFFu + ((u >> 16) & 1);
    return (unsigned short)(u >> 16);
}

// ------- kernel 1: per-channel mean of y; also zeroes the loss output -------
__global__ __launch_bounds__(256) void kmean(const float* __restrict__ y,
                                             float* __restrict__ ymu,
                                             float* __restrict__ out){
    const int c = blockIdx.x;
    const int t = threadIdx.x;
    if(c == 0 && t == 0) out[0] = 0.f;
    float s = 0.f;
    for(int n = 0; n < NBATCH; n++){
        const float4* p = reinterpret_cast<const float4*>(y + ((size_t)n*CC + c)*HW);
        #pragma unroll
        for(int i = 0; i < 4; i++){
            float4 v = p[i*256 + t];
            s += (v.x + v.y) + (v.z + v.w);
        }
    }
    __shared__ float red[256];
    red[t] = s; __syncthreads();
    for(int off = 128; off > 0; off >>= 1){
        if(t < off) red[t] += red[t+off];
        __syncthreads();
    }
    if(t == 0) ymu[c] = red[0] * (1.0f/((float)NBATCH*HW));
}

// ---- kernel 2: center, normalize over C, emit MFMA-fragment-major FP8 ----
// fp8 layout per batch (1 MB): addr(i,c) = (i>>4)*4096 + kt*512 + q*128 + (i&15)*8 + e
//   where c = kt*32 + q*8 + e.  blockIdx.z selects x vs y (de-serialized).
// Also inits dmink/rowsum/colmaxk (z==0 blocks only).
#define TROW 266
__global__ __launch_bounds__(256) void knorm(const float* __restrict__ x,
                                             const float* __restrict__ y,
                                             const float* __restrict__ ymu,
                                             unsigned char* __restrict__ xF,
                                             unsigned char* __restrict__ yF,
                                             unsigned* __restrict__ dmink,
                                             float* __restrict__ rowsum,
                                             unsigned* __restrict__ colmaxk){
    __shared__ __align__(16) unsigned short tile[64*TROW];
    __shared__ float invn[64];
    __shared__ float partial16[16][64];
    __shared__ float smu[CC];
    const int t   = threadIdx.x;
    const int hw0 = blockIdx.x * 64;
    const int n   = blockIdx.y;
    const int which = blockIdx.z;
    if(which == 0 && t < 64){
        size_t g = (size_t)n*HW + hw0 + t;
        dmink[g] = 0xFFFFFFFFu;
        rowsum[g] = 0.f;
        colmaxk[g] = 0u;
    }
    for(int c = t; c < CC; c += 256) smu[c] = ymu[c];
    const int cgrp = t >> 4;   // 0..15
    const int hwg  = t & 15;   // 0..15 (x4 hw each)
    const float* __restrict__ src = which ? y : x;
    unsigned char* __restrict__ dst = which ? yF : xF;
    __syncthreads();
    float ss4[4] = {0.f, 0.f, 0.f, 0.f};
    #pragma unroll
    for(int cc = 0; cc < 16; cc++){
        int c = cc*16 + cgrp;
        float4 v4 = *reinterpret_cast<const float4*>(
            &src[((size_t)n*CC + c)*HW + hw0 + hwg*4]);
        float mu = smu[c];
        float f0 = v4.x - mu, f1 = v4.y - mu, f2 = v4.z - mu, f3 = v4.w - mu;
        ss4[0] += f0*f0; ss4[1] += f1*f1; ss4[2] += f2*f2; ss4[3] += f3*f3;
        tile[(hwg*4+0)*TROW + c] = f2bf(f0);
        tile[(hwg*4+1)*TROW + c] = f2bf(f1);
        tile[(hwg*4+2)*TROW + c] = f2bf(f2);
        tile[(hwg*4+3)*TROW + c] = f2bf(f3);
    }
    #pragma unroll
    for(int e = 0; e < 4; e++) partial16[cgrp][hwg*4+e] = ss4[e];
    __syncthreads();
    if(t < 64){
        float s = 0.f;
        #pragma unroll
        for(int g2 = 0; g2 < 16; g2++) s += partial16[g2][t];
        invn[t] = rsqrtf(s);
    }
    __syncthreads();
    size_t base = ((size_t)n << 20) + (size_t)(hw0 >> 4)*4096;
    #pragma unroll
    for(int v4i = 0; v4i < 4; v4i++){
        int g  = v4i*256 + t;           // 0..1023, unit = 16 fp8 (2 rows x 8 c)
        int it = g >> 8;
        int kt = (g >> 5) & 7;
        int qq = (g >> 3) & 3;
        int u  = g & 7;
        int r0 = it*16 + u*2;
        unsigned w[4];
        #pragma unroll
        for(int rr = 0; rr < 2; rr++){
            int r = r0 + rr;
            float inv = invn[r];
            const unsigned* lp = reinterpret_cast<const unsigned*>(&tile[r*TROW + kt*32 + qq*8]);
            float f[8];
            #pragma unroll
            for(int w2 = 0; w2 < 4; w2++){
                unsigned uu = lp[w2];
                f[2*w2]   = __uint_as_float((uu & 0xFFFFu) << 16) * inv;
                f[2*w2+1] = __uint_as_float(uu & 0xFFFF0000u) * inv;
            }
            unsigned wa = 0, wb = 0;
            wa = __builtin_amdgcn_cvt_pk_fp8_f32(f[0], f[1], wa, false);
            wa = __builtin_amdgcn_cvt_pk_fp8_f32(f[2], f[3], wa, true);
            wb = __builtin_amdgcn_cvt_pk_fp8_f32(f[4], f[5], wb, false);
            wb = __builtin_amdgcn_cvt_pk_fp8_f32(f[6], f[7], wb, true);
            w[2*rr] = wa; w[2*rr+1] = wb;
        }
        uint4 ov; ov.x=w[0]; ov.y=w[1]; ov.z=w[2]; ov.w=w[3];
        *reinterpret_cast<uint4*>(dst + base + it*4096 + kt*512 + qq*128 + u*16) = ov;
    }
}

// ---- sweep kernels: block = 512 i (4 waves x 128 i in regs) x 512-j slice.
// EXACT R13 body (best measured: 48.8us/sweep).  Register budget is at the
// 2-wave/SIMD edge (252/256): do NOT add live values to the epilogues —
// R11's breg[] and R14's bb-fold both spilled to scratch (70-200MB WRITE).
// MODE 0: dmin   1: rowsum (scalar C2L)   2: colmax (sc4+bb4, -1 sub)
template<int MODE>
__global__ __launch_bounds__(256, 2) void ksweep(
        const unsigned char* __restrict__ xF,
        const unsigned char* __restrict__ yF,
        unsigned* __restrict__ dmink,
        float* __restrict__ rowsum,
        unsigned* __restrict__ colmaxk){
    __shared__ __align__(16) unsigned char Bs[2][16384];
    __shared__ __align__(16) float scS[4][128];
    __shared__ __align__(16) float bbS[4][128];
    const int t    = threadIdx.x;
    const int lane = t & 63;
    const int wave = t >> 6;
    const int q    = lane >> 4;
    const int l15  = lane & 15;
    const int bid  = blockIdx.x;
    const int n    = bid & 7;          // batch <-> XCD affinity
    const int rem  = bid >> 3;
    const int ip   = rem & 7;          // i-panel (512 rows)
    const int jq   = rem >> 3;         // j slice (512 cols)
    const size_t nb8 = (size_t)n << 20;
    const size_t nbw = (size_t)n * HW;
    const int iw   = ip*512 + wave*128;   // this wave's 128 rows
    const unsigned char* Ax = xF + nb8 + (size_t)(iw >> 4)*4096 + q*512 + l15*8;
    const unsigned char* Yb = yF + nb8 + (size_t)jq*131072;   // 512 j * 256 B

    // A fragments: af0 = k[q*32..+32), af1 = k[128+q*32..+32)
    U8 af0[8], af1[8];
    #pragma unroll
    for(int ti = 0; ti < 8; ti++)
        #pragma unroll
        for(int qq = 0; qq < 4; qq++){
            af0[ti].d[qq] = *reinterpret_cast<const llong*>(Ax + ti*4096 + qq*128);
            af1[ti].d[qq] = *reinterpret_cast<const llong*>(Ax + ti*4096 + 2048 + qq*128);
        }

    if(MODE >= 1){
        // per-row sc (and bb) -> wave-private broadcast LDS (2 rows per lane)
        #pragma unroll
        for(int rr = 0; rr < 2; rr++){
            int row = lane*2 + rr;
            size_t g = nbw + iw + row;
            scS[wave][row] = (2.f / (fdec(dmink[g]) + EPSF)) * LOG2E;
            if(MODE == 2) bbS[wave][row] = C2L - __log2f(rowsum[g]);
        }
    }
    float racc[8][4];
    #pragma unroll
    for(int ti = 0; ti < 8; ti++)
        #pragma unroll
        for(int r = 0; r < 4; r++) racc[ti][r] = (MODE == 0) ? -3e38f : 0.f;

    // prologue: stage super-tile 0 (16KB; 4KB per wave = 4 x 1KB chunks)
    #pragma unroll
    for(int p = 0; p < 4; p++){
        int c = wave*4 + p;
        GLDS(Yb + c*1024 + (size_t)lane*16, &Bs[0][c*1024]);
    }
    __syncthreads();

    #pragma unroll 1
    for(int ss = 0; ss < 8; ss++){
        // stage next super-tile (ss=7 overreads 16KB into slack; harmless)
        {
            const unsigned char* src = Yb + (size_t)(ss+1)*16384;
            unsigned char* dstb = Bs[(ss+1)&1];
            #pragma unroll
            for(int p = 0; p < 4; p++){
                int c = wave*4 + p;
                GLDS(src + c*1024 + (size_t)lane*16, &dstb[c*1024]);
            }
        }
        #pragma unroll 1
        for(int u = 0; u < 4; u++){
            const unsigned char* Bq = &Bs[ss&1][u*4096] + q*512 + l15*8;
            const int js = ss*4 + u;
            U8 b0, b1;
            #pragma unroll
            for(int qq = 0; qq < 4; qq++){
                b0.d[qq] = *reinterpret_cast<const llong*>(Bq + qq*128);
                b1.d[qq] = *reinterpret_cast<const llong*>(Bq + 2048 + qq*128);
            }
            floatx4 acc[8];
            #pragma unroll
            for(int a = 0; a < 8; a++) acc[a] = (floatx4){0.f,0.f,0.f,0.f};
            #pragma unroll
            for(int ti = 0; ti < 8; ti++){
                acc[ti] = __builtin_amdgcn_mfma_scale_f32_16x16x128_f8f6f4(
                              af0[ti].v, b0.v, acc[ti], 0, 0, 0, SCL1, 0, SCL1);
                acc[ti] = __builtin_amdgcn_mfma_scale_f32_16x16x128_f8f6f4(
                              af1[ti].v, b1.v, acc[ti], 0, 0, 0, SCL1, 0, SCL1);
            }
            if(MODE == 0){
                #pragma unroll
                for(int ti = 0; ti < 8; ti++)
                    #pragma unroll
                    for(int r = 0; r < 4; r++)
                        racc[ti][r] = fmaxf(racc[ti][r], acc[ti][r]);
            } else if(MODE == 1){
                #pragma unroll
                for(int ti = 0; ti < 8; ti++){
                    const floatx4 sc4 = *reinterpret_cast<const floatx4*>(&scS[wave][ti*16 + q*4]);
                    #pragma unroll
                    for(int r = 0; r < 4; r++)
                        racc[ti][r] += EXP2(fmaf(acc[ti][r] - 1.f, sc4[r], C2L));
                }
            } else {
                float a = -3e38f;
                #pragma unroll
                for(int ti = 0; ti < 8; ti++){
                    const floatx4 sc4 = *reinterpret_cast<const floatx4*>(&scS[wave][ti*16 + q*4]);
                    const floatx4 bb4 = *reinterpret_cast<const floatx4*>(&bbS[wave][ti*16 + q*4]);
                    #pragma unroll
                    for(int r = 0; r < 4; r++)
                        a = fmaxf(a, fmaf(acc[ti][r] - 1.f, sc4[r], bb4[r]));
                }
                a = fmaxf(a, __shfl_xor(a, 16));
                a = fmaxf(a, __shfl_xor(a, 32));
                if(lane < 16)
                    atomicMax(&colmaxk[nbw + jq*512 + js*16 + l15], fkey(EXP2(a)));
            }
        }
        __syncthreads();
    }

    if(MODE == 0){
        #pragma unroll
        for(int ti = 0; ti < 8; ti++)
            #pragma unroll
            for(int r = 0; r < 4; r++){
                float v = racc[ti][r];
                v = fmaxf(v, __shfl_xor(v, 1));
                v = fmaxf(v, __shfl_xor(v, 2));
                v = fmaxf(v, __shfl_xor(v, 4));
                v = fmaxf(v, __shfl_xor(v, 8));
                if(l15 == 0)
                    atomicMin(&dmink[nbw + iw + ti*16 + q*4 + r], fkey(1.f - v));
            }
    } else if(MODE == 1){
        #pragma unroll
        for(int ti = 0; ti < 8; ti++)
            #pragma unroll
            for(int r = 0; r < 4; r++){
                float v = racc[ti][r];
                v += __shfl_xor(v, 1);
                v += __shfl_xor(v, 2);
                v += __shfl_xor(v, 4);
                v += __shfl_xor(v, 8);
                if(l15 == 0)
                    atomicAdd(&rowsum[nbw + iw + ti*16 + q*4 + r], v);
            }
    }
}

// ------- final: per-batch partial reduced straight into out[0] -------
__global__ __launch_bounds__(256) void kpart(const unsigned* __restrict__ colmaxk,
                                             float* __restrict__ out){
    __shared__ float red[256];
    const int t = threadIdx.x;
    const int n = blockIdx.x;
    float s = 0.f;
    for(int j = t; j < HW; j += 256) s += fdec(colmaxk[(size_t)n*HW + j]);
    red[t] = s; __syncthreads();
    for(int off = 128; off > 0; off >>= 1){
        if(t < off) red[t] += red[t+off];
        __syncthreads();
    }
    if(t == 0) atomicAdd(out, -logf(red[0]*(1.0f/HW) + EPSF) * (1.0f/NBATCH));
}

extern "C" void kernel_launch(void* const* d_in, const int* in_sizes, int n_in,
                              void* d_out, int out_size, void* d_ws, size_t ws_size,
                              hipStream_t stream){
    const float* x = (const float*)d_in[0];
    const float* y = (const float*)d_in[1];
    float* out = (float*)d_out;
    char* ws = (char*)d_ws;

    float* ymu = (float*)ws;
    size_t off = 1024;
    unsigned char* xF = (unsigned char*)(ws + off); off += (size_t)NBATCH << 20;
    unsigned char* yF = (unsigned char*)(ws + off); off += ((size_t)NBATCH << 20) + (512<<10); // tail-prefetch slack
    unsigned* dmink   = (unsigned*)(ws + off);      off += (size_t)NBATCH*HW*4;
    float* rowsum     = (float*)(ws + off);         off += (size_t)NBATCH*HW*4;
    unsigned* colmaxk = (unsigned*)(ws + off);      off += (size_t)NBATCH*HW*4;

    kmean<<<dim3(CC), dim3(256), 0, stream>>>(y, ymu, out);
    knorm<<<dim3(HW/64, NBATCH, 2), dim3(256), 0, stream>>>(x, y, ymu, xF, yF,
                                                            dmink, rowsum, colmaxk);
    ksweep<0><<<dim3(512), dim3(256), 0, stream>>>(xF, yF, dmink, rowsum, colmaxk);
    ksweep<1><<<dim3(512), dim3(256), 0, stream>>>(xF, yF, dmink, rowsum, colmaxk);
    ksweep<2><<<dim3(512), dim3(256), 0, stream>>>(xF, yF, dmink, rowsum, colmaxk);
    kpart<<<dim3(NBATCH), dim3(256), 0, stream>>>(colmaxk, out);
}